// Round 11
// baseline (144.652 us; speedup 1.0000x reference)
//
#include <hip/hip_runtime.h>
#include <hip/hip_bf16.h>

// Problem constants
#define NB  2      // batch
#define CC  256    // channels
#define NHD 8      // heads
#define HD  32     // head dim
#define NT  4096   // tokens = H*W

typedef __bf16 bf16x8 __attribute__((ext_vector_type(8)));
typedef bf16x8 bf16x8_ma __attribute__((may_alias));
typedef __bf16 bf16x4 __attribute__((ext_vector_type(4)));
typedef bf16x4 bf16x4_ma __attribute__((may_alias));
typedef float  f32x4  __attribute__((ext_vector_type(4)));
typedef f32x4  f32x4_ma __attribute__((may_alias));
typedef float  f32x16 __attribute__((ext_vector_type(16)));
typedef unsigned int u32x4 __attribute__((ext_vector_type(4)));
typedef unsigned short u16x8 __attribute__((ext_vector_type(8)));

static __device__ __forceinline__ f32x4 zero4() {
    f32x4 z = {0.f, 0.f, 0.f, 0.f}; return z;
}
static __device__ __forceinline__ f32x16 zero16() {
    f32x16 z = {0.f,0.f,0.f,0.f,0.f,0.f,0.f,0.f,
                0.f,0.f,0.f,0.f,0.f,0.f,0.f,0.f};
    return z;
}

// q pre-scale: log2(e) / sqrt(32)
#define QSCALE 0.25505392421795654f

// v_cvt_pk_bf16_f32: dst.lo = bf16(lo), dst.hi = bf16(hi)  (no builtin on gfx950)
#define CVT_PK(dst, lo, hi_) \
    asm("v_cvt_pk_bf16_f32 %0, %1, %2" : "=v"(dst) : "v"(lo), "v"(hi_))
// v_permlane32_swap_b32: x[32:63] <-> y[0:31]
#define PLSWAP(x, y) \
    asm("v_permlane32_swap_b32 %0, %1" : "+v"(x), "+v"(y))

// ---------------------------------------------------------------------------
// ROUND 28: R27 resubmit (container died twice, no counters; audit found no
// wedging defect; R23->R24 precedent says infra flake). Defensive tweaks:
// rcpf builtin -> plain division in projc_k; no design change.
//  (1) attn: 128-j tiles, 4 subtiles per vmcnt(0) drain (compute ~900cy >
//      stage ~600cy -> drain amortized; barriers halved), l on MFMA pipe.
//  (2) projc_k: proj with fused JSEG combine -- B-stage reads PO/PL,
//      (o0+o1)/l, cvt_pk->bf16, ds_write into lane-order BF tile.
// ---------------------------------------------------------------------------

// ---------------------------------------------------------------------------
// Kernel 0: f32 -> bf16 convert, both weight arrays in one launch.
// ---------------------------------------------------------------------------
__global__ __launch_bounds__(256) void convw_k(const float* __restrict__ s1,
                                               __bf16* __restrict__ d1, int n1,
                                               const float* __restrict__ s2,
                                               __bf16* __restrict__ d2, int n2) {
    const int i = blockIdx.x * 256 + threadIdx.x;
    if (i < n1) d1[i] = (__bf16)s1[i];
    else if (i - n1 < n2) d2[i - n1] = (__bf16)s2[i - n1];
}

// ---------------------------------------------------------------------------
// Kernel 1: LDS-tiled transpose+convert x f32 [b][c][n] -> xt bf16 [b][n][c].
// ---------------------------------------------------------------------------
__global__ __launch_bounds__(256) void transpose_k(const float* __restrict__ x,
                                                   __bf16* __restrict__ xt) {
    __shared__ __bf16 T[64][65];
    const int tid = threadIdx.x;
    const int n0 = blockIdx.x * 64, c0 = blockIdx.y * 64, b = blockIdx.z;

#pragma unroll
    for (int rep = 0; rep < 16; ++rep) {
        const int e = rep * 256 + tid;
        const int cl = e >> 6, nl = e & 63;
        T[nl][cl] = (__bf16)x[((size_t)(b * CC + c0 + cl)) * NT + n0 + nl];
    }
    __syncthreads();
#pragma unroll
    for (int rep = 0; rep < 16; ++rep) {
        const int e = rep * 256 + tid;
        const int nl = e >> 6, cl = e & 63;
        xt[((size_t)(b * NT + n0 + nl)) * CC + c0 + cl] = T[nl][cl];
    }
}

// ---------------------------------------------------------------------------
// Kernel 2: QKV GEMM (MFMA), B-tile LDS-shared (proven R24).
// grid (NT/64, 768/64, NB), block 256.
// ---------------------------------------------------------------------------
__global__ __launch_bounds__(256) void qkv_k(const __bf16* __restrict__ wqkv,
                                             const __bf16* __restrict__ xt,
                                             __bf16* __restrict__ qt,
                                             __bf16* __restrict__ kt,
                                             __bf16* __restrict__ vv) {
    __shared__ __align__(16) __bf16 BF[4][8][512];   // [js][kc][lane*8] 32 KB

    const int lane = threadIdx.x & 63, wv = threadIdx.x >> 6;
    const int g = lane >> 4, c16 = lane & 15;
    const int b    = blockIdx.z;
    const int o0   = blockIdx.y * 64 + wv * 16;
    const int tok0 = blockIdx.x * 64;

    // Stage B-tile: wave wv stages js=wv, kc=0..7 (1 KB chunks, lane-order).
    const __bf16* bsrc = xt + ((size_t)(b * NT + tok0 + wv * 16 + c16)) * CC + g * 8;
#pragma unroll
    for (int kc = 0; kc < 8; ++kc) {
        __builtin_amdgcn_global_load_lds(
            (const __attribute__((address_space(1))) void*)(bsrc + kc * 32),
            (__attribute__((address_space(3))) void*)&BF[wv][kc][0],
            16, 0, 0);
    }

    // Preload A rows (o0+c16, all 8 k-chunks) while the stage is in flight.
    const __bf16* arow = wqkv + (size_t)(o0 + c16) * CC + g * 8;
    bf16x8 a[8];
#pragma unroll
    for (int kc = 0; kc < 8; ++kc) a[kc] = *(const bf16x8_ma*)(arow + kc * 32);

    __syncthreads();   // drains vmcnt(0): stage + A-loads complete

    f32x4 acc[4];
#pragma unroll
    for (int i = 0; i < 4; ++i) acc[i] = zero4();

#pragma unroll
    for (int kc = 0; kc < 8; ++kc) {
#pragma unroll
        for (int js = 0; js < 4; ++js) {
            bf16x8 bb = *(const bf16x8_ma*)&BF[js][kc][lane * 8];
            acc[js] = __builtin_amdgcn_mfma_f32_16x16x32_bf16(a[kc], bb, acc[js], 0, 0, 0);
        }
    }

    const int reg = o0 >> 8;                 // 0=q, 1=k, 2=v (wave-uniform)
    const int oo0 = (o0 & 255) + g * 4;
    const int h   = oo0 >> 5;
    const int dd0 = oo0 & 31;
    const size_t bh = (size_t)(b * NHD + h);

#pragma unroll
    for (int js = 0; js < 4; ++js) {
        const int tok = tok0 + js * 16 + c16;
        if (reg == 0) {
            bf16x4 pk;
#pragma unroll
            for (int r = 0; r < 4; ++r) pk[r] = (__bf16)(acc[js][r] * QSCALE);
            *(bf16x4_ma*)(qt + (bh * NT + tok) * HD + dd0) = pk;
        } else if (reg == 1) {
            bf16x4 pk;
#pragma unroll
            for (int r = 0; r < 4; ++r) pk[r] = (__bf16)acc[js][r];
            *(bf16x4_ma*)(kt + (bh * NT + tok) * HD + dd0) = pk;
        } else {
#pragma unroll
            for (int r = 0; r < 4; ++r)
                vv[(bh * HD + dd0 + r) * NT + tok] = (__bf16)acc[js][r];
        }
    }
}

// ---------------------------------------------------------------------------
// Kernel 3: MFMA flash attention, 32x32 swapped-operand, in-register P,
// block-shared LDS K/V (2-phase), 128-j tiles (4 subtiles per drain), l on
// the MFMA pipe (ones-B). Block 256 = 4 waves x 32 q = 128 q/block; block
// sweeps its gridDim.z j-segment. Per 128-j tile: wave stages 4 chunks
// (K js=wv halves, V js=wv halves); compute = 4 subtiles (24 MFMAs).
// JSEG=2: f32 partial (O,l) to PO/PL; JSEG=1: ao directly.
// grid (NT/128, NB*NHD, JSEG), LDS 32KB, 4 blocks/CU.
// ---------------------------------------------------------------------------
__global__ __launch_bounds__(256, 4) void attn_k(const __bf16* __restrict__ qt,
                                                 const __bf16* __restrict__ kt,
                                                 const __bf16* __restrict__ vv,
                                                 __bf16* __restrict__ ao,
                                                 float* __restrict__ PO,
                                                 float* __restrict__ PL) {
    // Fragment lane-order tiles: [buf][js][half][lane*8 bf16]
    __shared__ __align__(16) __bf16 KF[2][4][2][512];   // 16 KB
    __shared__ __align__(16) __bf16 VF[2][4][2][512];   // 16 KB

    const int tid  = threadIdx.x;
    const int lane = tid & 63, wv = tid >> 6;          // wv 0..3
    const int c32 = lane & 31, hi = lane >> 5;
    const int bh = blockIdx.y;
    const int b = bh >> 3, h = bh & 7;
    const int seg = blockIdx.z, nseg = gridDim.z;
    const int i0q = blockIdx.x * 128 + wv * 32;        // this wave: 32 queries

    const __bf16* qbase = qt + ((size_t)bh * NT + i0q) * HD;
    const __bf16* kbase = kt + (size_t)bh * NT * HD;
    const __bf16* vbase = vv + (size_t)bh * HD * NT;

    // Q fragments (B operand of score MFMA): row=q=c32, k = kk*16 + hi*8 + e
    bf16x8 aq0 = *(const bf16x8_ma*)(qbase + (size_t)c32 * HD + hi * 8);
    bf16x8 aq1 = *(const bf16x8_ma*)(qbase + (size_t)c32 * HD + 16 + hi * 8);

    // All-ones bf16 B operand (layout-independent: every element is 1.0).
    u16x8 ones_u = {0x3F80,0x3F80,0x3F80,0x3F80,0x3F80,0x3F80,0x3F80,0x3F80};
    const bf16x8 ones = __builtin_bit_cast(bf16x8, ones_u);

    f32x16 oacc = zero16();      // D[q_row][d_col]: rows=q, cols=d=c32
    f32x16 lacc = zero16();      // row-sums of P, replicated across cols

// Stage one 128-j tile: wave wv stages its js=wv subtile of K and V (4 x 1KB).
#define STAGE(bf, jb) do {                                                              \
    const __bf16* gk = kbase + (size_t)((jb) + wv * 32 + c32) * HD + hi * 8;            \
    __builtin_amdgcn_global_load_lds(                                                   \
        (const __attribute__((address_space(1))) void*)gk,                              \
        (__attribute__((address_space(3))) void*)&KF[bf][wv][0][0],                     \
        16, 0, 0);                                                                      \
    __builtin_amdgcn_global_load_lds(                                                   \
        (const __attribute__((address_space(1))) void*)(gk + 16),                       \
        (__attribute__((address_space(3))) void*)&KF[bf][wv][1][0],                     \
        16, 0, 0);                                                                      \
    const __bf16* gv = vbase + (size_t)c32 * NT + (jb) + wv * 32 + hi * 8;              \
    __builtin_amdgcn_global_load_lds(                                                   \
        (const __attribute__((address_space(1))) void*)gv,                              \
        (__attribute__((address_space(3))) void*)&VF[bf][wv][0][0],                     \
        16, 0, 0);                                                                      \
    __builtin_amdgcn_global_load_lds(                                                   \
        (const __attribute__((address_space(1))) void*)(gv + 16),                       \
        (__attribute__((address_space(3))) void*)&VF[bf][wv][1][0],                     \
        16, 0, 0);                                                                      \
} while (0)

#define SUBTILE(bf, js) do {                                                            \
    bf16x8 fk0 = *(const bf16x8_ma*)&KF[bf][js][0][lane * 8];                           \
    bf16x8 fk1 = *(const bf16x8_ma*)&KF[bf][js][1][lane * 8];                           \
    bf16x8 fv0 = *(const bf16x8_ma*)&VF[bf][js][0][lane * 8];                           \
    bf16x8 fv1 = *(const bf16x8_ma*)&VF[bf][js][1][lane * 8];                           \
    f32x16 s = __builtin_amdgcn_mfma_f32_32x32x16_bf16(fk0, aq0, zero16(), 0, 0, 0);    \
    s = __builtin_amdgcn_mfma_f32_32x32x16_bf16(fk1, aq1, s, 0, 0, 0);                  \
    float p[16];                                                                        \
    _Pragma("unroll")                                                                   \
    for (int r = 0; r < 16; ++r) p[r] = __builtin_amdgcn_exp2f(s[r]);                   \
    unsigned pk[8];                                                                     \
    _Pragma("unroll")                                                                   \
    for (int i = 0; i < 8; ++i) CVT_PK(pk[i], p[2 * i], p[2 * i + 1]);                  \
    PLSWAP(pk[0], pk[2]);                                                               \
    PLSWAP(pk[1], pk[3]);                                                               \
    PLSWAP(pk[4], pk[6]);                                                               \
    PLSWAP(pk[5], pk[7]);                                                               \
    u32x4 a0 = {pk[0], pk[1], pk[2], pk[3]};                                            \
    u32x4 a1 = {pk[4], pk[5], pk[6], pk[7]};                                            \
    const bf16x8 ap0 = __builtin_bit_cast(bf16x8, a0);                                  \
    const bf16x8 ap1 = __builtin_bit_cast(bf16x8, a1);                                  \
    oacc = __builtin_amdgcn_mfma_f32_32x32x16_bf16(ap0, fv0, oacc, 0, 0, 0);            \
    oacc = __builtin_amdgcn_mfma_f32_32x32x16_bf16(ap1, fv1, oacc, 0, 0, 0);            \
    lacc = __builtin_amdgcn_mfma_f32_32x32x16_bf16(ap0, ones, lacc, 0, 0, 0);           \
    lacc = __builtin_amdgcn_mfma_f32_32x32x16_bf16(ap1, ones, lacc, 0, 0, 0);           \
} while (0)

    const int ntiles  = (NT / 128) / nseg;         // 16 @ jseg=2, 32 @ jseg=1
    const int j_begin = seg * ntiles * 128;

    // Prologue: stage tile 0 into buf 0.
    STAGE(0, j_begin);
    asm volatile("s_waitcnt vmcnt(0)" ::: "memory");
    __syncthreads();

    int buf = 0;
#pragma unroll 1
    for (int t = 0; t < ntiles; ++t) {
        if (t + 1 < ntiles) STAGE(buf ^ 1, j_begin + (t + 1) * 128);
        SUBTILE(buf, 0);
        SUBTILE(buf, 1);
        SUBTILE(buf, 2);
        SUBTILE(buf, 3);
        asm volatile("s_waitcnt vmcnt(0)" ::: "memory");
        __syncthreads();
        buf ^= 1;
    }

#undef STAGE
#undef SUBTILE

    if (nseg == 1) {
        // Direct epilogue: oacc/lacc rows q = 8*g4 + 4*hi + r, cols d = c32.
#pragma unroll
        for (int g4 = 0; g4 < 4; ++g4) {
#pragma unroll
            for (int r = 0; r < 4; ++r) {
                const int q = 8 * g4 + 4 * hi + r;
                ao[((size_t)(b * NT) + i0q + q) * CC + h * HD + c32] =
                    (__bf16)(oacc[4 * g4 + r] / lacc[4 * g4 + r]);
            }
        }
    } else {
        // Partial epilogue: PO [seg][bh][n][32] f32, PL [seg][bh][n] f32.
        float* po = PO + (((size_t)seg * NB * NHD + bh) * NT + i0q) * HD;
#pragma unroll
        for (int g4 = 0; g4 < 4; ++g4) {
#pragma unroll
            for (int r = 0; r < 4; ++r) {
                const int q = 8 * g4 + 4 * hi + r;
                po[(size_t)q * HD + c32] = oacc[4 * g4 + r];
            }
        }
        if (c32 == 0) {
            float* pl = PL + ((size_t)seg * NB * NHD + bh) * NT + i0q;
#pragma unroll
            for (int g4 = 0; g4 < 4; ++g4)
#pragma unroll
                for (int r = 0; r < 4; ++r)
                    pl[8 * g4 + 4 * hi + r] = lacc[4 * g4 + r];
        }
    }
}

// ---------------------------------------------------------------------------
// Kernel 4a: proj GEMM + residual, JSEG=1 path (reads bf16 ao).
// grid (NT/64, CC/64, NB), block 256.
// ---------------------------------------------------------------------------
__global__ __launch_bounds__(256) void proj_k(const __bf16* __restrict__ wp,
                                              const __bf16* __restrict__ ao,
                                              const float* __restrict__ x,
                                              float* __restrict__ out) {
    __shared__ __align__(16) __bf16 BF[4][8][512];   // [js][kc][lane*8] 32 KB

    const int lane = threadIdx.x & 63, wv = threadIdx.x >> 6;
    const int g = lane >> 4, c16 = lane & 15;
    const int b    = blockIdx.z;
    const int o0   = blockIdx.y * 64 + wv * 16;
    const int tok0 = blockIdx.x * 64;

    const __bf16* bsrc = ao + ((size_t)(b * NT + tok0 + wv * 16 + c16)) * CC + g * 8;
#pragma unroll
    for (int kc = 0; kc < 8; ++kc) {
        __builtin_amdgcn_global_load_lds(
            (const __attribute__((address_space(1))) void*)(bsrc + kc * 32),
            (__attribute__((address_space(3))) void*)&BF[wv][kc][0],
            16, 0, 0);
    }

    const __bf16* arow = wp + (size_t)(o0 + c16) * CC + g * 8;
    bf16x8 a[8];
#pragma unroll
    for (int kc = 0; kc < 8; ++kc) a[kc] = *(const bf16x8_ma*)(arow + kc * 32);

    __syncthreads();

    f32x4 acc[4];
#pragma unroll
    for (int i = 0; i < 4; ++i) acc[i] = zero4();

#pragma unroll
    for (int kc = 0; kc < 8; ++kc) {
#pragma unroll
        for (int js = 0; js < 4; ++js) {
            bf16x8 bb = *(const bf16x8_ma*)&BF[js][kc][lane * 8];
            acc[js] = __builtin_amdgcn_mfma_f32_16x16x32_bf16(a[kc], bb, acc[js], 0, 0, 0);
        }
    }

#pragma unroll
    for (int js = 0; js < 4; ++js) {
        const int tok = tok0 + js * 16 + c16;
#pragma unroll
        for (int r = 0; r < 4; ++r) {
            const int o = o0 + g * 4 + r;
            const size_t idx = ((size_t)(b * CC + o)) * NT + tok;
            out[idx] = acc[js][r] + x[idx];
        }
    }
}

// ---------------------------------------------------------------------------
// Kernel 4b: proj GEMM + residual, JSEG=2 path with FUSED combine.
// B-stage reads PO(seg0)+PO(seg1)+PL, computes (o0+o1)/l, packs bf16 via
// cvt_pk, writes into the same lane-order BF tile. ao never materialized.
// grid (NT/64, CC/64, NB), block 256.
// ---------------------------------------------------------------------------
__global__ __launch_bounds__(256) void projc_k(const __bf16* __restrict__ wp,
                                               const float* __restrict__ PO,
                                               const float* __restrict__ PL,
                                               const float* __restrict__ x,
                                               float* __restrict__ out) {
    __shared__ __align__(16) __bf16 BF[4][8][512];   // [js][kc][lane*8] 32 KB

    const int lane = threadIdx.x & 63, wv = threadIdx.x >> 6;
    const int g = lane >> 4, c16 = lane & 15;
    const int b    = blockIdx.z;
    const int o0   = blockIdx.y * 64 + wv * 16;
    const int tok0 = blockIdx.x * 64;

    // A preload first (independent of BF).
    const __bf16* arow = wp + (size_t)(o0 + c16) * CC + g * 8;
    bf16x8 a[8];
#pragma unroll
    for (int kc = 0; kc < 8; ++kc) a[kc] = *(const bf16x8_ma*)(arow + kc * 32);

    // Fused combine-stage: chunk (wv, kc) holds ao[tok=tok0+wv*16+c16]
    // [c=kc*32+g*8 .. +7], i.e. h=kc, d=g*8..g*8+7.
    const int ntok = tok0 + wv * 16 + c16;
    const size_t SEGO = (size_t)(NB * NHD) * NT * HD;
    const size_t SEGL = (size_t)(NB * NHD) * NT;
#pragma unroll
    for (int kc = 0; kc < 8; ++kc) {
        const size_t bhn = (size_t)(b * NHD + kc) * NT + ntok;
        const size_t poi = bhn * HD + g * 8;
        f32x4 oa0 = *(const f32x4_ma*)&PO[poi];
        f32x4 ob0 = *(const f32x4_ma*)&PO[poi + 4];
        f32x4 oa1 = *(const f32x4_ma*)&PO[SEGO + poi];
        f32x4 ob1 = *(const f32x4_ma*)&PO[SEGO + poi + 4];
        const float l = PL[bhn] + PL[SEGL + bhn];
        const float rl = 1.0f / l;
        unsigned pk[4];
        CVT_PK(pk[0], (oa0[0] + oa1[0]) * rl, (oa0[1] + oa1[1]) * rl);
        CVT_PK(pk[1], (oa0[2] + oa1[2]) * rl, (oa0[3] + oa1[3]) * rl);
        CVT_PK(pk[2], (ob0[0] + ob1[0]) * rl, (ob0[1] + ob1[1]) * rl);
        CVT_PK(pk[3], (ob0[2] + ob1[2]) * rl, (ob0[3] + ob1[3]) * rl);
        u32x4 u = {pk[0], pk[1], pk[2], pk[3]};
        *(bf16x8_ma*)&BF[wv][kc][lane * 8] = __builtin_bit_cast(bf16x8, u);
    }

    __syncthreads();

    f32x4 acc[4];
#pragma unroll
    for (int i = 0; i < 4; ++i) acc[i] = zero4();

#pragma unroll
    for (int kc = 0; kc < 8; ++kc) {
#pragma unroll
        for (int js = 0; js < 4; ++js) {
            bf16x8 bb = *(const bf16x8_ma*)&BF[js][kc][lane * 8];
            acc[js] = __builtin_amdgcn_mfma_f32_16x16x32_bf16(a[kc], bb, acc[js], 0, 0, 0);
        }
    }

#pragma unroll
    for (int js = 0; js < 4; ++js) {
        const int tok = tok0 + js * 16 + c16;
#pragma unroll
        for (int r = 0; r < 4; ++r) {
            const int o = o0 + g * 4 + r;
            const size_t idx = ((size_t)(b * CC + o)) * NT + tok;
            out[idx] = acc[js][r] + x[idx];
        }
    }
}

// ---------------------------------------------------------------------------
extern "C" void kernel_launch(void* const* d_in, const int* in_sizes, int n_in,
                              void* d_out, int out_size, void* d_ws, size_t ws_size,
                              hipStream_t stream) {
    const int SX  = NB * CC * NT;   // 2,097,152
    const int SW3 = 3 * CC * CC;    //   196,608
    const int SW1 = CC * CC;        //    65,536
    const size_t E = (size_t)SX;

    const float* x  = nullptr;
    const float* wq = nullptr;
    const float* wp = nullptr;
    for (int i = 0; i < n_in; ++i) {
        const int sz = in_sizes[i];
        if (sz == SX || sz == 2 * SX || sz == 4 * SX)           x  = (const float*)d_in[i];
        else if (sz == SW3 || sz == 2 * SW3 || sz == 4 * SW3)   wq = (const float*)d_in[i];
        else if (sz == SW1 || sz == 2 * SW1 || sz == 4 * SW1)   wp = (const float*)d_in[i];
    }
    if (!x || !wq || !wp) {
        x  = (const float*)d_in[0];
        wq = (const float*)d_in[1];
        wp = (const float*)d_in[2];
    }

    // Workspace (bf16 elements), base 17.3 MB (proven):
    __bf16* ws  = (__bf16*)d_ws;
    __bf16* wqb = ws;
    __bf16* wpb = wqb + SW3;
    __bf16* xt  = wpb + SW1;             // becomes ao after qkv_k (JSEG=1 path)
    __bf16* qt  = xt + E;
    __bf16* kt  = qt + E;
    __bf16* vv  = kt + E;
    __bf16* ao  = xt;

    // Optional JSEG=2 partial buffers (f32), appended after vv:
    const size_t baseB = (size_t)(SW3 + SW1) * 2 + 4 * E * 2;       // bytes used
    const size_t poB   = 2ull * NB * NHD * NT * HD * 4;             // 16.78 MB
    const size_t plB   = 2ull * NB * NHD * NT * 4;                  //  0.52 MB
    const int jseg = (ws_size >= baseB + poB + plB) ? 2 : 1;
    float* PO = (float*)((char*)d_ws + baseB);
    float* PL = (float*)((char*)d_ws + baseB + poB);

    float* out = (float*)d_out;

    convw_k<<<dim3((SW3 + SW1 + 255) / 256), 256, 0, stream>>>(wq, wqb, SW3, wp, wpb, SW1);
    transpose_k<<<dim3(NT / 64, CC / 64, NB), 256, 0, stream>>>(x, xt);
    qkv_k<<<dim3(NT / 64, (3 * CC) / 64, NB), 256, 0, stream>>>(wqb, xt, qt, kt, vv);
    attn_k<<<dim3(NT / 128, NB * NHD, jseg), 256, 0, stream>>>(qt, kt, vv, ao, PO, PL);
    if (jseg == 2)
        projc_k<<<dim3(NT / 64, CC / 64, NB), 256, 0, stream>>>(wpb, PO, PL, x, out);
    else
        proj_k<<<dim3(NT / 64, CC / 64, NB), 256, 0, stream>>>(wpb, ao, x, out);
}

// Round 12
// 144.552 us; speedup vs baseline: 1.0007x; 1.0007x over previous
//
#include <hip/hip_runtime.h>
#include <hip/hip_bf16.h>

// Problem constants
#define NB  2      // batch
#define CC  256    // channels
#define NHD 8      // heads
#define HD  32     // head dim
#define NT  4096   // tokens = H*W

typedef __bf16 bf16x8 __attribute__((ext_vector_type(8)));
typedef bf16x8 bf16x8_ma __attribute__((may_alias));
typedef __bf16 bf16x4 __attribute__((ext_vector_type(4)));
typedef bf16x4 bf16x4_ma __attribute__((may_alias));
typedef float  f32x4  __attribute__((ext_vector_type(4)));
typedef f32x4  f32x4_ma __attribute__((may_alias));
typedef float  f32x16 __attribute__((ext_vector_type(16)));
typedef unsigned int u32x4 __attribute__((ext_vector_type(4)));
typedef unsigned short u16x8 __attribute__((ext_vector_type(8)));

static __device__ __forceinline__ f32x4 zero4() {
    f32x4 z = {0.f, 0.f, 0.f, 0.f}; return z;
}
static __device__ __forceinline__ f32x16 zero16() {
    f32x16 z = {0.f,0.f,0.f,0.f,0.f,0.f,0.f,0.f,
                0.f,0.f,0.f,0.f,0.f,0.f,0.f,0.f};
    return z;
}

// q pre-scale: log2(e) / sqrt(32)
#define QSCALE 0.25505392421795654f

// v_cvt_pk_bf16_f32: dst.lo = bf16(lo), dst.hi = bf16(hi)  (no builtin on gfx950)
#define CVT_PK(dst, lo, hi_) \
    asm("v_cvt_pk_bf16_f32 %0, %1, %2" : "=v"(dst) : "v"(lo), "v"(hi_))
// v_permlane32_swap_b32: x[32:63] <-> y[0:31]
#define PLSWAP(x, y) \
    asm("v_permlane32_swap_b32 %0, %1" : "+v"(x), "+v"(y))

// ---------------------------------------------------------------------------
// ROUND 29: R28 post-mortem -- attn 128-j tiles won (58.1->55.3) but projc_k
// fusion REGRESSED ~11us vs separate proj+comb (f32 PO doubles staging bytes
// + combine serialized before the single barrier). Revert to proven proj_k +
// comb_k. attn occupancy is grid-starved again (29.5% = 2.4 blk/CU resident
// vs demand exactly 4): JSEG 2->4 gives 2048 blocks = 8 blk/CU demand
// (5 resident by LDS), K/V line-requests UNCHANGED (block reads only its
// j-quarter); cost = PO write 16.8->33.6MB. comb_k sums nseg partials.
// Workspace-guarded fallback 4->2->1.
// ---------------------------------------------------------------------------

// ---------------------------------------------------------------------------
// Kernel 0: f32 -> bf16 convert, both weight arrays in one launch.
// ---------------------------------------------------------------------------
__global__ __launch_bounds__(256) void convw_k(const float* __restrict__ s1,
                                               __bf16* __restrict__ d1, int n1,
                                               const float* __restrict__ s2,
                                               __bf16* __restrict__ d2, int n2) {
    const int i = blockIdx.x * 256 + threadIdx.x;
    if (i < n1) d1[i] = (__bf16)s1[i];
    else if (i - n1 < n2) d2[i - n1] = (__bf16)s2[i - n1];
}

// ---------------------------------------------------------------------------
// Kernel 1: LDS-tiled transpose+convert x f32 [b][c][n] -> xt bf16 [b][n][c].
// ---------------------------------------------------------------------------
__global__ __launch_bounds__(256) void transpose_k(const float* __restrict__ x,
                                                   __bf16* __restrict__ xt) {
    __shared__ __bf16 T[64][65];
    const int tid = threadIdx.x;
    const int n0 = blockIdx.x * 64, c0 = blockIdx.y * 64, b = blockIdx.z;

#pragma unroll
    for (int rep = 0; rep < 16; ++rep) {
        const int e = rep * 256 + tid;
        const int cl = e >> 6, nl = e & 63;
        T[nl][cl] = (__bf16)x[((size_t)(b * CC + c0 + cl)) * NT + n0 + nl];
    }
    __syncthreads();
#pragma unroll
    for (int rep = 0; rep < 16; ++rep) {
        const int e = rep * 256 + tid;
        const int nl = e >> 6, cl = e & 63;
        xt[((size_t)(b * NT + n0 + nl)) * CC + c0 + cl] = T[nl][cl];
    }
}

// ---------------------------------------------------------------------------
// Kernel 2: QKV GEMM (MFMA), B-tile LDS-shared (proven R24).
// grid (NT/64, 768/64, NB), block 256.
// ---------------------------------------------------------------------------
__global__ __launch_bounds__(256) void qkv_k(const __bf16* __restrict__ wqkv,
                                             const __bf16* __restrict__ xt,
                                             __bf16* __restrict__ qt,
                                             __bf16* __restrict__ kt,
                                             __bf16* __restrict__ vv) {
    __shared__ __align__(16) __bf16 BF[4][8][512];   // [js][kc][lane*8] 32 KB

    const int lane = threadIdx.x & 63, wv = threadIdx.x >> 6;
    const int g = lane >> 4, c16 = lane & 15;
    const int b    = blockIdx.z;
    const int o0   = blockIdx.y * 64 + wv * 16;
    const int tok0 = blockIdx.x * 64;

    // Stage B-tile: wave wv stages js=wv, kc=0..7 (1 KB chunks, lane-order).
    const __bf16* bsrc = xt + ((size_t)(b * NT + tok0 + wv * 16 + c16)) * CC + g * 8;
#pragma unroll
    for (int kc = 0; kc < 8; ++kc) {
        __builtin_amdgcn_global_load_lds(
            (const __attribute__((address_space(1))) void*)(bsrc + kc * 32),
            (__attribute__((address_space(3))) void*)&BF[wv][kc][0],
            16, 0, 0);
    }

    // Preload A rows (o0+c16, all 8 k-chunks) while the stage is in flight.
    const __bf16* arow = wqkv + (size_t)(o0 + c16) * CC + g * 8;
    bf16x8 a[8];
#pragma unroll
    for (int kc = 0; kc < 8; ++kc) a[kc] = *(const bf16x8_ma*)(arow + kc * 32);

    __syncthreads();   // drains vmcnt(0): stage + A-loads complete

    f32x4 acc[4];
#pragma unroll
    for (int i = 0; i < 4; ++i) acc[i] = zero4();

#pragma unroll
    for (int kc = 0; kc < 8; ++kc) {
#pragma unroll
        for (int js = 0; js < 4; ++js) {
            bf16x8 bb = *(const bf16x8_ma*)&BF[js][kc][lane * 8];
            acc[js] = __builtin_amdgcn_mfma_f32_16x16x32_bf16(a[kc], bb, acc[js], 0, 0, 0);
        }
    }

    const int reg = o0 >> 8;                 // 0=q, 1=k, 2=v (wave-uniform)
    const int oo0 = (o0 & 255) + g * 4;
    const int h   = oo0 >> 5;
    const int dd0 = oo0 & 31;
    const size_t bh = (size_t)(b * NHD + h);

#pragma unroll
    for (int js = 0; js < 4; ++js) {
        const int tok = tok0 + js * 16 + c16;
        if (reg == 0) {
            bf16x4 pk;
#pragma unroll
            for (int r = 0; r < 4; ++r) pk[r] = (__bf16)(acc[js][r] * QSCALE);
            *(bf16x4_ma*)(qt + (bh * NT + tok) * HD + dd0) = pk;
        } else if (reg == 1) {
            bf16x4 pk;
#pragma unroll
            for (int r = 0; r < 4; ++r) pk[r] = (__bf16)acc[js][r];
            *(bf16x4_ma*)(kt + (bh * NT + tok) * HD + dd0) = pk;
        } else {
#pragma unroll
            for (int r = 0; r < 4; ++r)
                vv[(bh * HD + dd0 + r) * NT + tok] = (__bf16)acc[js][r];
        }
    }
}

// ---------------------------------------------------------------------------
// Kernel 3: MFMA flash attention, 32x32 swapped-operand, in-register P,
// block-shared LDS K/V (2-phase), 128-j tiles (4 subtiles per drain), l on
// the MFMA pipe (ones-B). Block 256 = 4 waves x 32 q = 128 q/block; block
// sweeps its gridDim.z j-segment (nseg = 1, 2, or 4).
// nseg>1: f32 partial (O,l) to PO/PL; nseg=1: ao directly.
// grid (NT/128, NB*NHD, JSEG), LDS 32KB.
// ---------------------------------------------------------------------------
__global__ __launch_bounds__(256, 4) void attn_k(const __bf16* __restrict__ qt,
                                                 const __bf16* __restrict__ kt,
                                                 const __bf16* __restrict__ vv,
                                                 __bf16* __restrict__ ao,
                                                 float* __restrict__ PO,
                                                 float* __restrict__ PL) {
    // Fragment lane-order tiles: [buf][js][half][lane*8 bf16]
    __shared__ __align__(16) __bf16 KF[2][4][2][512];   // 16 KB
    __shared__ __align__(16) __bf16 VF[2][4][2][512];   // 16 KB

    const int tid  = threadIdx.x;
    const int lane = tid & 63, wv = tid >> 6;          // wv 0..3
    const int c32 = lane & 31, hi = lane >> 5;
    const int bh = blockIdx.y;
    const int b = bh >> 3, h = bh & 7;
    const int seg = blockIdx.z, nseg = gridDim.z;
    const int i0q = blockIdx.x * 128 + wv * 32;        // this wave: 32 queries

    const __bf16* qbase = qt + ((size_t)bh * NT + i0q) * HD;
    const __bf16* kbase = kt + (size_t)bh * NT * HD;
    const __bf16* vbase = vv + (size_t)bh * HD * NT;

    // Q fragments (B operand of score MFMA): row=q=c32, k = kk*16 + hi*8 + e
    bf16x8 aq0 = *(const bf16x8_ma*)(qbase + (size_t)c32 * HD + hi * 8);
    bf16x8 aq1 = *(const bf16x8_ma*)(qbase + (size_t)c32 * HD + 16 + hi * 8);

    // All-ones bf16 B operand (layout-independent: every element is 1.0).
    u16x8 ones_u = {0x3F80,0x3F80,0x3F80,0x3F80,0x3F80,0x3F80,0x3F80,0x3F80};
    const bf16x8 ones = __builtin_bit_cast(bf16x8, ones_u);

    f32x16 oacc = zero16();      // D[q_row][d_col]: rows=q, cols=d=c32
    f32x16 lacc = zero16();      // row-sums of P, replicated across cols

// Stage one 128-j tile: wave wv stages its js=wv subtile of K and V (4 x 1KB).
#define STAGE(bf, jb) do {                                                              \
    const __bf16* gk = kbase + (size_t)((jb) + wv * 32 + c32) * HD + hi * 8;            \
    __builtin_amdgcn_global_load_lds(                                                   \
        (const __attribute__((address_space(1))) void*)gk,                              \
        (__attribute__((address_space(3))) void*)&KF[bf][wv][0][0],                     \
        16, 0, 0);                                                                      \
    __builtin_amdgcn_global_load_lds(                                                   \
        (const __attribute__((address_space(1))) void*)(gk + 16),                       \
        (__attribute__((address_space(3))) void*)&KF[bf][wv][1][0],                     \
        16, 0, 0);                                                                      \
    const __bf16* gv = vbase + (size_t)c32 * NT + (jb) + wv * 32 + hi * 8;              \
    __builtin_amdgcn_global_load_lds(                                                   \
        (const __attribute__((address_space(1))) void*)gv,                              \
        (__attribute__((address_space(3))) void*)&VF[bf][wv][0][0],                     \
        16, 0, 0);                                                                      \
    __builtin_amdgcn_global_load_lds(                                                   \
        (const __attribute__((address_space(1))) void*)(gv + 16),                       \
        (__attribute__((address_space(3))) void*)&VF[bf][wv][1][0],                     \
        16, 0, 0);                                                                      \
} while (0)

#define SUBTILE(bf, js) do {                                                            \
    bf16x8 fk0 = *(const bf16x8_ma*)&KF[bf][js][0][lane * 8];                           \
    bf16x8 fk1 = *(const bf16x8_ma*)&KF[bf][js][1][lane * 8];                           \
    bf16x8 fv0 = *(const bf16x8_ma*)&VF[bf][js][0][lane * 8];                           \
    bf16x8 fv1 = *(const bf16x8_ma*)&VF[bf][js][1][lane * 8];                           \
    f32x16 s = __builtin_amdgcn_mfma_f32_32x32x16_bf16(fk0, aq0, zero16(), 0, 0, 0);    \
    s = __builtin_amdgcn_mfma_f32_32x32x16_bf16(fk1, aq1, s, 0, 0, 0);                  \
    float p[16];                                                                        \
    _Pragma("unroll")                                                                   \
    for (int r = 0; r < 16; ++r) p[r] = __builtin_amdgcn_exp2f(s[r]);                   \
    unsigned pk[8];                                                                     \
    _Pragma("unroll")                                                                   \
    for (int i = 0; i < 8; ++i) CVT_PK(pk[i], p[2 * i], p[2 * i + 1]);                  \
    PLSWAP(pk[0], pk[2]);                                                               \
    PLSWAP(pk[1], pk[3]);                                                               \
    PLSWAP(pk[4], pk[6]);                                                               \
    PLSWAP(pk[5], pk[7]);                                                               \
    u32x4 a0 = {pk[0], pk[1], pk[2], pk[3]};                                            \
    u32x4 a1 = {pk[4], pk[5], pk[6], pk[7]};                                            \
    const bf16x8 ap0 = __builtin_bit_cast(bf16x8, a0);                                  \
    const bf16x8 ap1 = __builtin_bit_cast(bf16x8, a1);                                  \
    oacc = __builtin_amdgcn_mfma_f32_32x32x16_bf16(ap0, fv0, oacc, 0, 0, 0);            \
    oacc = __builtin_amdgcn_mfma_f32_32x32x16_bf16(ap1, fv1, oacc, 0, 0, 0);            \
    lacc = __builtin_amdgcn_mfma_f32_32x32x16_bf16(ap0, ones, lacc, 0, 0, 0);           \
    lacc = __builtin_amdgcn_mfma_f32_32x32x16_bf16(ap1, ones, lacc, 0, 0, 0);           \
} while (0)

    const int ntiles  = (NT / 128) / nseg;         // 8 @ jseg=4, 16 @ 2, 32 @ 1
    const int j_begin = seg * ntiles * 128;

    // Prologue: stage tile 0 into buf 0.
    STAGE(0, j_begin);
    asm volatile("s_waitcnt vmcnt(0)" ::: "memory");
    __syncthreads();

    int buf = 0;
#pragma unroll 1
    for (int t = 0; t < ntiles; ++t) {
        if (t + 1 < ntiles) STAGE(buf ^ 1, j_begin + (t + 1) * 128);
        SUBTILE(buf, 0);
        SUBTILE(buf, 1);
        SUBTILE(buf, 2);
        SUBTILE(buf, 3);
        asm volatile("s_waitcnt vmcnt(0)" ::: "memory");
        __syncthreads();
        buf ^= 1;
    }

#undef STAGE
#undef SUBTILE

    if (nseg == 1) {
        // Direct epilogue: oacc/lacc rows q = 8*g4 + 4*hi + r, cols d = c32.
#pragma unroll
        for (int g4 = 0; g4 < 4; ++g4) {
#pragma unroll
            for (int r = 0; r < 4; ++r) {
                const int q = 8 * g4 + 4 * hi + r;
                ao[((size_t)(b * NT) + i0q + q) * CC + h * HD + c32] =
                    (__bf16)(oacc[4 * g4 + r] / lacc[4 * g4 + r]);
            }
        }
    } else {
        // Partial epilogue: PO [seg][bh][n][32] f32, PL [seg][bh][n] f32.
        float* po = PO + (((size_t)seg * NB * NHD + bh) * NT + i0q) * HD;
#pragma unroll
        for (int g4 = 0; g4 < 4; ++g4) {
#pragma unroll
            for (int r = 0; r < 4; ++r) {
                const int q = 8 * g4 + 4 * hi + r;
                po[(size_t)q * HD + c32] = oacc[4 * g4 + r];
            }
        }
        if (c32 == 0) {
            float* pl = PL + ((size_t)seg * NB * NHD + bh) * NT + i0q;
#pragma unroll
            for (int g4 = 0; g4 < 4; ++g4)
#pragma unroll
                for (int r = 0; r < 4; ++r)
                    pl[8 * g4 + 4 * hi + r] = lacc[4 * g4 + r];
        }
    }
}

// ---------------------------------------------------------------------------
// Kernel 3b: combine nseg partials: ao = (Sum O_s)/(Sum l_s), bf16.
// One thread = 4 consecutive d of one (bh, n). grid 2048 x 256.
// ---------------------------------------------------------------------------
__global__ __launch_bounds__(256) void comb_k(const float* __restrict__ PO,
                                              const float* __restrict__ PL,
                                              __bf16* __restrict__ ao,
                                              int nseg) {
    const int i = blockIdx.x * 256 + threadIdx.x;    // 0 .. 16*4096*8-1
    const int bh = i >> 15;                          // 8 groups * 4096 n
    const int rem = i & 32767;
    const int n = rem >> 3, g = rem & 7;
    const int b = bh >> 3, h = bh & 7;

    const size_t SEGO = (size_t)(NB * NHD) * NT * HD;
    const size_t SEGL = (size_t)(NB * NHD) * NT;
    const size_t o0i = (((size_t)bh) * NT + n) * HD + g * 4;
    const size_t li  = (size_t)bh * NT + n;

    f32x4 o = *(const f32x4_ma*)&PO[o0i];
    float l = PL[li];
#pragma unroll 3
    for (int s = 1; s < nseg; ++s) {
        o += *(const f32x4_ma*)&PO[(size_t)s * SEGO + o0i];
        l += PL[(size_t)s * SEGL + li];
    }

    bf16x4 pk;
#pragma unroll
    for (int r = 0; r < 4; ++r) pk[r] = (__bf16)(o[r] / l);
    *(bf16x4_ma*)&ao[((size_t)(b * NT) + n) * CC + h * HD + g * 4] = pk;
}

// ---------------------------------------------------------------------------
// Kernel 4: proj GEMM + residual (MFMA), F32 output, B-tile LDS-shared
// (proven R24/R26 form).
// grid (NT/64, CC/64, NB), block 256.
// ---------------------------------------------------------------------------
__global__ __launch_bounds__(256) void proj_k(const __bf16* __restrict__ wp,
                                              const __bf16* __restrict__ ao,
                                              const float* __restrict__ x,
                                              float* __restrict__ out) {
    __shared__ __align__(16) __bf16 BF[4][8][512];   // [js][kc][lane*8] 32 KB

    const int lane = threadIdx.x & 63, wv = threadIdx.x >> 6;
    const int g = lane >> 4, c16 = lane & 15;
    const int b    = blockIdx.z;
    const int o0   = blockIdx.y * 64 + wv * 16;
    const int tok0 = blockIdx.x * 64;

    const __bf16* bsrc = ao + ((size_t)(b * NT + tok0 + wv * 16 + c16)) * CC + g * 8;
#pragma unroll
    for (int kc = 0; kc < 8; ++kc) {
        __builtin_amdgcn_global_load_lds(
            (const __attribute__((address_space(1))) void*)(bsrc + kc * 32),
            (__attribute__((address_space(3))) void*)&BF[wv][kc][0],
            16, 0, 0);
    }

    const __bf16* arow = wp + (size_t)(o0 + c16) * CC + g * 8;
    bf16x8 a[8];
#pragma unroll
    for (int kc = 0; kc < 8; ++kc) a[kc] = *(const bf16x8_ma*)(arow + kc * 32);

    __syncthreads();

    f32x4 acc[4];
#pragma unroll
    for (int i = 0; i < 4; ++i) acc[i] = zero4();

#pragma unroll
    for (int kc = 0; kc < 8; ++kc) {
#pragma unroll
        for (int js = 0; js < 4; ++js) {
            bf16x8 bb = *(const bf16x8_ma*)&BF[js][kc][lane * 8];
            acc[js] = __builtin_amdgcn_mfma_f32_16x16x32_bf16(a[kc], bb, acc[js], 0, 0, 0);
        }
    }

#pragma unroll
    for (int js = 0; js < 4; ++js) {
        const int tok = tok0 + js * 16 + c16;
#pragma unroll
        for (int r = 0; r < 4; ++r) {
            const int o = o0 + g * 4 + r;
            const size_t idx = ((size_t)(b * CC + o)) * NT + tok;
            out[idx] = acc[js][r] + x[idx];
        }
    }
}

// ---------------------------------------------------------------------------
extern "C" void kernel_launch(void* const* d_in, const int* in_sizes, int n_in,
                              void* d_out, int out_size, void* d_ws, size_t ws_size,
                              hipStream_t stream) {
    const int SX  = NB * CC * NT;   // 2,097,152
    const int SW3 = 3 * CC * CC;    //   196,608
    const int SW1 = CC * CC;        //    65,536
    const size_t E = (size_t)SX;

    const float* x  = nullptr;
    const float* wq = nullptr;
    const float* wp = nullptr;
    for (int i = 0; i < n_in; ++i) {
        const int sz = in_sizes[i];
        if (sz == SX || sz == 2 * SX || sz == 4 * SX)           x  = (const float*)d_in[i];
        else if (sz == SW3 || sz == 2 * SW3 || sz == 4 * SW3)   wq = (const float*)d_in[i];
        else if (sz == SW1 || sz == 2 * SW1 || sz == 4 * SW1)   wp = (const float*)d_in[i];
    }
    if (!x || !wq || !wp) {
        x  = (const float*)d_in[0];
        wq = (const float*)d_in[1];
        wp = (const float*)d_in[2];
    }

    // Workspace (bf16 elements), base 17.3 MB (proven):
    __bf16* ws  = (__bf16*)d_ws;
    __bf16* wqb = ws;
    __bf16* wpb = wqb + SW3;
    __bf16* xt  = wpb + SW1;             // becomes ao after qkv_k
    __bf16* qt  = xt + E;
    __bf16* kt  = qt + E;
    __bf16* vv  = kt + E;
    __bf16* ao  = xt;

    // Optional JSEG partial buffers (f32), appended after vv:
    const size_t baseB = (size_t)(SW3 + SW1) * 2 + 4 * E * 2;       // bytes used
    const size_t segoB = (size_t)NB * NHD * NT * HD * 4;            // 8.39 MB/seg
    const size_t seglB = (size_t)NB * NHD * NT * 4;                 // 0.26 MB/seg
    int jseg = 1;
    if (ws_size >= baseB + 4 * (segoB + seglB)) jseg = 4;
    else if (ws_size >= baseB + 2 * (segoB + seglB)) jseg = 2;
    float* PO = (float*)((char*)d_ws + baseB);
    float* PL = (float*)((char*)d_ws + baseB + (size_t)jseg * segoB);

    float* out = (float*)d_out;

    convw_k<<<dim3((SW3 + SW1 + 255) / 256), 256, 0, stream>>>(wq, wqb, SW3, wp, wpb, SW1);
    transpose_k<<<dim3(NT / 64, CC / 64, NB), 256, 0, stream>>>(x, xt);
    qkv_k<<<dim3(NT / 64, (3 * CC) / 64, NB), 256, 0, stream>>>(wqb, xt, qt, kt, vv);
    attn_k<<<dim3(NT / 128, NB * NHD, jseg), 256, 0, stream>>>(qt, kt, vv, ao, PO, PL);
    if (jseg > 1)
        comb_k<<<dim3((NB * NHD * NT * (HD / 4)) / 256), 256, 0, stream>>>(PO, PL, ao, jseg);
    proj_k<<<dim3(NT / 64, CC / 64, NB), 256, 0, stream>>>(wpb, ao, x, out);
}

// Round 13
// 141.562 us; speedup vs baseline: 1.0218x; 1.0211x over previous
//
#include <hip/hip_runtime.h>
#include <hip/hip_bf16.h>

// Problem constants
#define NB  2      // batch
#define CC  256    // channels
#define NHD 8      // heads
#define HD  32     // head dim
#define NT  4096   // tokens = H*W

typedef __bf16 bf16x8 __attribute__((ext_vector_type(8)));
typedef bf16x8 bf16x8_ma __attribute__((may_alias));
typedef __bf16 bf16x4 __attribute__((ext_vector_type(4)));
typedef bf16x4 bf16x4_ma __attribute__((may_alias));
typedef float  f32x4  __attribute__((ext_vector_type(4)));
typedef f32x4  f32x4_ma __attribute__((may_alias));
typedef float  f32x16 __attribute__((ext_vector_type(16)));
typedef unsigned int u32x4 __attribute__((ext_vector_type(4)));
typedef unsigned short u16x8 __attribute__((ext_vector_type(8)));

static __device__ __forceinline__ f32x4 zero4() {
    f32x4 z = {0.f, 0.f, 0.f, 0.f}; return z;
}
static __device__ __forceinline__ f32x16 zero16() {
    f32x16 z = {0.f,0.f,0.f,0.f,0.f,0.f,0.f,0.f,
                0.f,0.f,0.f,0.f,0.f,0.f,0.f,0.f};
    return z;
}

// q pre-scale: log2(e) / sqrt(32)
#define QSCALE 0.25505392421795654f

// v_cvt_pk_bf16_f32: dst.lo = bf16(lo), dst.hi = bf16(hi)  (no builtin on gfx950)
#define CVT_PK(dst, lo, hi_) \
    asm("v_cvt_pk_bf16_f32 %0, %1, %2" : "=v"(dst) : "v"(lo), "v"(hi_))
// v_permlane32_swap_b32: x[32:63] <-> y[0:31]
#define PLSWAP(x, y) \
    asm("v_permlane32_swap_b32 %0, %1" : "+v"(x), "+v"(y))

// ---------------------------------------------------------------------------
// ROUND 30: R29 post-mortem -- JSEG=4 null for attn (occupancy didn't scale;
// 55.9us) and cost ~3us in comb (PO 33.8MB). Revert JSEG=2. Attack the
// non-attn 88us: transpose_k (50MB HBM round-trip + launch, ~10-15us) exists
// only to feed qkv a transposed B operand -- fold it INTO qkv's LDS staging:
// stage x f32 directly (f32x4 token-coalesced), cvt+scatter ds_write_b16
// into a [tok][264]-pitch bf16 tile (2-way bank alias on both sides = free,
// m136), MFMA reads B fragments straight from it. Bit-identical math; net
// -33.5MB traffic, -1 kernel. attn/comb/proj unchanged (proven).
// ---------------------------------------------------------------------------

// ---------------------------------------------------------------------------
// Kernel 0: f32 -> bf16 convert, both weight arrays in one launch.
// ---------------------------------------------------------------------------
__global__ __launch_bounds__(256) void convw_k(const float* __restrict__ s1,
                                               __bf16* __restrict__ d1, int n1,
                                               const float* __restrict__ s2,
                                               __bf16* __restrict__ d2, int n2) {
    const int i = blockIdx.x * 256 + threadIdx.x;
    if (i < n1) d1[i] = (__bf16)s1[i];
    else if (i - n1 < n2) d2[i - n1] = (__bf16)s2[i - n1];
}

// ---------------------------------------------------------------------------
// Kernel 2: QKV GEMM (MFMA) with FUSED transpose+convert staging.
// Block = 64 o x 64 tok. Stage: x f32 [b][c][NT] loaded f32x4 token-major
// (coalesced 256B per quarter-wave), converted bf16, scattered into
// T[tok][c] (pitch 264, 2-way bank alias = free). MFMA B fragments read
// directly from T (b128, stride 528B -> 2-way alias = free).
// q pre-scaled by QSCALE. qt/kt token-major [bh][n][32], vv d-major.
// grid (NT/64, 768/64, NB), block 256. LDS 33.8 KB.
// ---------------------------------------------------------------------------
__global__ __launch_bounds__(256) void qkv_k(const __bf16* __restrict__ wqkv,
                                             const float* __restrict__ x,
                                             __bf16* __restrict__ qt,
                                             __bf16* __restrict__ kt,
                                             __bf16* __restrict__ vv) {
    __shared__ __align__(16) __bf16 T[64][264];   // [tok][c+pad] 33792 B

    const int tid  = threadIdx.x;
    const int lane = tid & 63, wv = tid >> 6;
    const int g = lane >> 4, c16 = lane & 15;
    const int b    = blockIdx.z;
    const int o0   = blockIdx.y * 64 + wv * 16;
    const int tok0 = blockIdx.x * 64;

    // Fused transpose stage: thread covers tok4..tok4+3 x 16 c-rows.
    {
        const int tok4 = (tid & 15) * 4;
        const int crow = tid >> 4;                 // 0..15
#pragma unroll
        for (int i = 0; i < 16; ++i) {
            const int c = i * 16 + crow;
            f32x4 v = *(const f32x4_ma*)&x[((size_t)(b * CC + c)) * NT + tok0 + tok4];
#pragma unroll
            for (int j = 0; j < 4; ++j)
                T[tok4 + j][c] = (__bf16)v[j];
        }
    }

    // Preload A rows (o0+c16, all 8 k-chunks) while stores are in flight.
    const __bf16* arow = wqkv + (size_t)(o0 + c16) * CC + g * 8;
    bf16x8 a[8];
#pragma unroll
    for (int kc = 0; kc < 8; ++kc) a[kc] = *(const bf16x8_ma*)(arow + kc * 32);

    __syncthreads();

    f32x4 acc[4];
#pragma unroll
    for (int i = 0; i < 4; ++i) acc[i] = zero4();

#pragma unroll
    for (int kc = 0; kc < 8; ++kc) {
#pragma unroll
        for (int js = 0; js < 4; ++js) {
            bf16x8 bb = *(const bf16x8_ma*)&T[js * 16 + c16][kc * 32 + g * 8];
            acc[js] = __builtin_amdgcn_mfma_f32_16x16x32_bf16(a[kc], bb, acc[js], 0, 0, 0);
        }
    }

    const int reg = o0 >> 8;                 // 0=q, 1=k, 2=v (wave-uniform)
    const int oo0 = (o0 & 255) + g * 4;
    const int h   = oo0 >> 5;
    const int dd0 = oo0 & 31;
    const size_t bh = (size_t)(b * NHD + h);

#pragma unroll
    for (int js = 0; js < 4; ++js) {
        const int tok = tok0 + js * 16 + c16;
        if (reg == 0) {
            bf16x4 pk;
#pragma unroll
            for (int r = 0; r < 4; ++r) pk[r] = (__bf16)(acc[js][r] * QSCALE);
            *(bf16x4_ma*)(qt + (bh * NT + tok) * HD + dd0) = pk;
        } else if (reg == 1) {
            bf16x4 pk;
#pragma unroll
            for (int r = 0; r < 4; ++r) pk[r] = (__bf16)acc[js][r];
            *(bf16x4_ma*)(kt + (bh * NT + tok) * HD + dd0) = pk;
        } else {
#pragma unroll
            for (int r = 0; r < 4; ++r)
                vv[(bh * HD + dd0 + r) * NT + tok] = (__bf16)acc[js][r];
        }
    }
}

// ---------------------------------------------------------------------------
// Kernel 3: MFMA flash attention, 32x32 swapped-operand, in-register P,
// block-shared LDS K/V (2-phase), 128-j tiles (4 subtiles per drain), l on
// the MFMA pipe (ones-B). Block 256 = 4 waves x 32 q = 128 q/block; block
// sweeps its gridDim.z j-segment (nseg = 1 or 2).
// nseg>1: f32 partial (O,l) to PO/PL; nseg=1: ao directly.
// grid (NT/128, NB*NHD, JSEG), LDS 32KB.
// ---------------------------------------------------------------------------
__global__ __launch_bounds__(256, 4) void attn_k(const __bf16* __restrict__ qt,
                                                 const __bf16* __restrict__ kt,
                                                 const __bf16* __restrict__ vv,
                                                 __bf16* __restrict__ ao,
                                                 float* __restrict__ PO,
                                                 float* __restrict__ PL) {
    // Fragment lane-order tiles: [buf][js][half][lane*8 bf16]
    __shared__ __align__(16) __bf16 KF[2][4][2][512];   // 16 KB
    __shared__ __align__(16) __bf16 VF[2][4][2][512];   // 16 KB

    const int tid  = threadIdx.x;
    const int lane = tid & 63, wv = tid >> 6;          // wv 0..3
    const int c32 = lane & 31, hi = lane >> 5;
    const int bh = blockIdx.y;
    const int b = bh >> 3, h = bh & 7;
    const int seg = blockIdx.z, nseg = gridDim.z;
    const int i0q = blockIdx.x * 128 + wv * 32;        // this wave: 32 queries

    const __bf16* qbase = qt + ((size_t)bh * NT + i0q) * HD;
    const __bf16* kbase = kt + (size_t)bh * NT * HD;
    const __bf16* vbase = vv + (size_t)bh * HD * NT;

    // Q fragments (B operand of score MFMA): row=q=c32, k = kk*16 + hi*8 + e
    bf16x8 aq0 = *(const bf16x8_ma*)(qbase + (size_t)c32 * HD + hi * 8);
    bf16x8 aq1 = *(const bf16x8_ma*)(qbase + (size_t)c32 * HD + 16 + hi * 8);

    // All-ones bf16 B operand (layout-independent: every element is 1.0).
    u16x8 ones_u = {0x3F80,0x3F80,0x3F80,0x3F80,0x3F80,0x3F80,0x3F80,0x3F80};
    const bf16x8 ones = __builtin_bit_cast(bf16x8, ones_u);

    f32x16 oacc = zero16();      // D[q_row][d_col]: rows=q, cols=d=c32
    f32x16 lacc = zero16();      // row-sums of P, replicated across cols

// Stage one 128-j tile: wave wv stages its js=wv subtile of K and V (4 x 1KB).
#define STAGE(bf, jb) do {                                                              \
    const __bf16* gk = kbase + (size_t)((jb) + wv * 32 + c32) * HD + hi * 8;            \
    __builtin_amdgcn_global_load_lds(                                                   \
        (const __attribute__((address_space(1))) void*)gk,                              \
        (__attribute__((address_space(3))) void*)&KF[bf][wv][0][0],                     \
        16, 0, 0);                                                                      \
    __builtin_amdgcn_global_load_lds(                                                   \
        (const __attribute__((address_space(1))) void*)(gk + 16),                       \
        (__attribute__((address_space(3))) void*)&KF[bf][wv][1][0],                     \
        16, 0, 0);                                                                      \
    const __bf16* gv = vbase + (size_t)c32 * NT + (jb) + wv * 32 + hi * 8;              \
    __builtin_amdgcn_global_load_lds(                                                   \
        (const __attribute__((address_space(1))) void*)gv,                              \
        (__attribute__((address_space(3))) void*)&VF[bf][wv][0][0],                     \
        16, 0, 0);                                                                      \
    __builtin_amdgcn_global_load_lds(                                                   \
        (const __attribute__((address_space(1))) void*)(gv + 16),                       \
        (__attribute__((address_space(3))) void*)&VF[bf][wv][1][0],                     \
        16, 0, 0);                                                                      \
} while (0)

#define SUBTILE(bf, js) do {                                                            \
    bf16x8 fk0 = *(const bf16x8_ma*)&KF[bf][js][0][lane * 8];                           \
    bf16x8 fk1 = *(const bf16x8_ma*)&KF[bf][js][1][lane * 8];                           \
    bf16x8 fv0 = *(const bf16x8_ma*)&VF[bf][js][0][lane * 8];                           \
    bf16x8 fv1 = *(const bf16x8_ma*)&VF[bf][js][1][lane * 8];                           \
    f32x16 s = __builtin_amdgcn_mfma_f32_32x32x16_bf16(fk0, aq0, zero16(), 0, 0, 0);    \
    s = __builtin_amdgcn_mfma_f32_32x32x16_bf16(fk1, aq1, s, 0, 0, 0);                  \
    float p[16];                                                                        \
    _Pragma("unroll")                                                                   \
    for (int r = 0; r < 16; ++r) p[r] = __builtin_amdgcn_exp2f(s[r]);                   \
    unsigned pk[8];                                                                     \
    _Pragma("unroll")                                                                   \
    for (int i = 0; i < 8; ++i) CVT_PK(pk[i], p[2 * i], p[2 * i + 1]);                  \
    PLSWAP(pk[0], pk[2]);                                                               \
    PLSWAP(pk[1], pk[3]);                                                               \
    PLSWAP(pk[4], pk[6]);                                                               \
    PLSWAP(pk[5], pk[7]);                                                               \
    u32x4 a0 = {pk[0], pk[1], pk[2], pk[3]};                                            \
    u32x4 a1 = {pk[4], pk[5], pk[6], pk[7]};                                            \
    const bf16x8 ap0 = __builtin_bit_cast(bf16x8, a0);                                  \
    const bf16x8 ap1 = __builtin_bit_cast(bf16x8, a1);                                  \
    oacc = __builtin_amdgcn_mfma_f32_32x32x16_bf16(ap0, fv0, oacc, 0, 0, 0);            \
    oacc = __builtin_amdgcn_mfma_f32_32x32x16_bf16(ap1, fv1, oacc, 0, 0, 0);            \
    lacc = __builtin_amdgcn_mfma_f32_32x32x16_bf16(ap0, ones, lacc, 0, 0, 0);           \
    lacc = __builtin_amdgcn_mfma_f32_32x32x16_bf16(ap1, ones, lacc, 0, 0, 0);           \
} while (0)

    const int ntiles  = (NT / 128) / nseg;         // 16 @ jseg=2, 32 @ jseg=1
    const int j_begin = seg * ntiles * 128;

    // Prologue: stage tile 0 into buf 0.
    STAGE(0, j_begin);
    asm volatile("s_waitcnt vmcnt(0)" ::: "memory");
    __syncthreads();

    int buf = 0;
#pragma unroll 1
    for (int t = 0; t < ntiles; ++t) {
        if (t + 1 < ntiles) STAGE(buf ^ 1, j_begin + (t + 1) * 128);
        SUBTILE(buf, 0);
        SUBTILE(buf, 1);
        SUBTILE(buf, 2);
        SUBTILE(buf, 3);
        asm volatile("s_waitcnt vmcnt(0)" ::: "memory");
        __syncthreads();
        buf ^= 1;
    }

#undef STAGE
#undef SUBTILE

    if (nseg == 1) {
        // Direct epilogue: oacc/lacc rows q = 8*g4 + 4*hi + r, cols d = c32.
#pragma unroll
        for (int g4 = 0; g4 < 4; ++g4) {
#pragma unroll
            for (int r = 0; r < 4; ++r) {
                const int q = 8 * g4 + 4 * hi + r;
                ao[((size_t)(b * NT) + i0q + q) * CC + h * HD + c32] =
                    (__bf16)(oacc[4 * g4 + r] / lacc[4 * g4 + r]);
            }
        }
    } else {
        // Partial epilogue: PO [seg][bh][n][32] f32, PL [seg][bh][n] f32.
        float* po = PO + (((size_t)seg * NB * NHD + bh) * NT + i0q) * HD;
#pragma unroll
        for (int g4 = 0; g4 < 4; ++g4) {
#pragma unroll
            for (int r = 0; r < 4; ++r) {
                const int q = 8 * g4 + 4 * hi + r;
                po[(size_t)q * HD + c32] = oacc[4 * g4 + r];
            }
        }
        if (c32 == 0) {
            float* pl = PL + ((size_t)seg * NB * NHD + bh) * NT + i0q;
#pragma unroll
            for (int g4 = 0; g4 < 4; ++g4)
#pragma unroll
                for (int r = 0; r < 4; ++r)
                    pl[8 * g4 + 4 * hi + r] = lacc[4 * g4 + r];
        }
    }
}

// ---------------------------------------------------------------------------
// Kernel 3b: combine nseg partials: ao = (Sum O_s)/(Sum l_s), bf16.
// One thread = 4 consecutive d of one (bh, n). grid 2048 x 256.
// ---------------------------------------------------------------------------
__global__ __launch_bounds__(256) void comb_k(const float* __restrict__ PO,
                                              const float* __restrict__ PL,
                                              __bf16* __restrict__ ao,
                                              int nseg) {
    const int i = blockIdx.x * 256 + threadIdx.x;    // 0 .. 16*4096*8-1
    const int bh = i >> 15;                          // 8 groups * 4096 n
    const int rem = i & 32767;
    const int n = rem >> 3, g = rem & 7;
    const int b = bh >> 3, h = bh & 7;

    const size_t SEGO = (size_t)(NB * NHD) * NT * HD;
    const size_t SEGL = (size_t)(NB * NHD) * NT;
    const size_t o0i = (((size_t)bh) * NT + n) * HD + g * 4;
    const size_t li  = (size_t)bh * NT + n;

    f32x4 o = *(const f32x4_ma*)&PO[o0i];
    float l = PL[li];
#pragma unroll 3
    for (int s = 1; s < nseg; ++s) {
        o += *(const f32x4_ma*)&PO[(size_t)s * SEGO + o0i];
        l += PL[(size_t)s * SEGL + li];
    }

    bf16x4 pk;
#pragma unroll
    for (int r = 0; r < 4; ++r) pk[r] = (__bf16)(o[r] / l);
    *(bf16x4_ma*)&ao[((size_t)(b * NT) + n) * CC + h * HD + g * 4] = pk;
}

// ---------------------------------------------------------------------------
// Kernel 4: proj GEMM + residual (MFMA), F32 output, B-tile LDS-shared
// (proven R24/R26 form).
// grid (NT/64, CC/64, NB), block 256.
// ---------------------------------------------------------------------------
__global__ __launch_bounds__(256) void proj_k(const __bf16* __restrict__ wp,
                                              const __bf16* __restrict__ ao,
                                              const float* __restrict__ x,
                                              float* __restrict__ out) {
    __shared__ __align__(16) __bf16 BF[4][8][512];   // [js][kc][lane*8] 32 KB

    const int lane = threadIdx.x & 63, wv = threadIdx.x >> 6;
    const int g = lane >> 4, c16 = lane & 15;
    const int b    = blockIdx.z;
    const int o0   = blockIdx.y * 64 + wv * 16;
    const int tok0 = blockIdx.x * 64;

    const __bf16* bsrc = ao + ((size_t)(b * NT + tok0 + wv * 16 + c16)) * CC + g * 8;
#pragma unroll
    for (int kc = 0; kc < 8; ++kc) {
        __builtin_amdgcn_global_load_lds(
            (const __attribute__((address_space(1))) void*)(bsrc + kc * 32),
            (__attribute__((address_space(3))) void*)&BF[wv][kc][0],
            16, 0, 0);
    }

    const __bf16* arow = wp + (size_t)(o0 + c16) * CC + g * 8;
    bf16x8 a[8];
#pragma unroll
    for (int kc = 0; kc < 8; ++kc) a[kc] = *(const bf16x8_ma*)(arow + kc * 32);

    __syncthreads();

    f32x4 acc[4];
#pragma unroll
    for (int i = 0; i < 4; ++i) acc[i] = zero4();

#pragma unroll
    for (int kc = 0; kc < 8; ++kc) {
#pragma unroll
        for (int js = 0; js < 4; ++js) {
            bf16x8 bb = *(const bf16x8_ma*)&BF[js][kc][lane * 8];
            acc[js] = __builtin_amdgcn_mfma_f32_16x16x32_bf16(a[kc], bb, acc[js], 0, 0, 0);
        }
    }

#pragma unroll
    for (int js = 0; js < 4; ++js) {
        const int tok = tok0 + js * 16 + c16;
#pragma unroll
        for (int r = 0; r < 4; ++r) {
            const int o = o0 + g * 4 + r;
            const size_t idx = ((size_t)(b * CC + o)) * NT + tok;
            out[idx] = acc[js][r] + x[idx];
        }
    }
}

// ---------------------------------------------------------------------------
extern "C" void kernel_launch(void* const* d_in, const int* in_sizes, int n_in,
                              void* d_out, int out_size, void* d_ws, size_t ws_size,
                              hipStream_t stream) {
    const int SX  = NB * CC * NT;   // 2,097,152
    const int SW3 = 3 * CC * CC;    //   196,608
    const int SW1 = CC * CC;        //    65,536
    const size_t E = (size_t)SX;

    const float* x  = nullptr;
    const float* wq = nullptr;
    const float* wp = nullptr;
    for (int i = 0; i < n_in; ++i) {
        const int sz = in_sizes[i];
        if (sz == SX || sz == 2 * SX || sz == 4 * SX)           x  = (const float*)d_in[i];
        else if (sz == SW3 || sz == 2 * SW3 || sz == 4 * SW3)   wq = (const float*)d_in[i];
        else if (sz == SW1 || sz == 2 * SW1 || sz == 4 * SW1)   wp = (const float*)d_in[i];
    }
    if (!x || !wq || !wp) {
        x  = (const float*)d_in[0];
        wq = (const float*)d_in[1];
        wp = (const float*)d_in[2];
    }

    // Workspace (bf16 elements), base 17.3 MB (proven layout kept; the old
    // xt slot is now only ao):
    __bf16* ws  = (__bf16*)d_ws;
    __bf16* wqb = ws;
    __bf16* wpb = wqb + SW3;
    __bf16* ao  = wpb + SW1;
    __bf16* qt  = ao + E;
    __bf16* kt  = qt + E;
    __bf16* vv  = kt + E;

    // Optional JSEG partial buffers (f32), appended after vv:
    const size_t baseB = (size_t)(SW3 + SW1) * 2 + 4 * E * 2;       // bytes used
    const size_t segoB = (size_t)NB * NHD * NT * HD * 4;            // 8.39 MB/seg
    const size_t seglB = (size_t)NB * NHD * NT * 4;                 // 0.26 MB/seg
    const int jseg = (ws_size >= baseB + 2 * (segoB + seglB)) ? 2 : 1;
    float* PO = (float*)((char*)d_ws + baseB);
    float* PL = (float*)((char*)d_ws + baseB + (size_t)jseg * segoB);

    float* out = (float*)d_out;

    convw_k<<<dim3((SW3 + SW1 + 255) / 256), 256, 0, stream>>>(wq, wqb, SW3, wp, wpb, SW1);
    qkv_k<<<dim3(NT / 64, (3 * CC) / 64, NB), 256, 0, stream>>>(wqb, x, qt, kt, vv);
    attn_k<<<dim3(NT / 128, NB * NHD, jseg), 256, 0, stream>>>(qt, kt, vv, ao, PO, PL);
    if (jseg > 1)
        comb_k<<<dim3((NB * NHD * NT * (HD / 4)) / 256), 256, 0, stream>>>(PO, PL, ao, jseg);
    proj_k<<<dim3(NT / 64, CC / 64, NB), 256, 0, stream>>>(wpb, ao, x, out);
}

// Round 14
// 140.202 us; speedup vs baseline: 1.0317x; 1.0097x over previous
//
#include <hip/hip_runtime.h>
#include <hip/hip_bf16.h>

// Problem constants
#define NB  2      // batch
#define CC  256    // channels
#define NHD 8      // heads
#define HD  32     // head dim
#define NT  4096   // tokens = H*W

typedef __bf16 bf16x8 __attribute__((ext_vector_type(8)));
typedef bf16x8 bf16x8_ma __attribute__((may_alias));
typedef __bf16 bf16x4 __attribute__((ext_vector_type(4)));
typedef bf16x4 bf16x4_ma __attribute__((may_alias));
typedef float  f32x4  __attribute__((ext_vector_type(4)));
typedef f32x4  f32x4_ma __attribute__((may_alias));
typedef float  f32x16 __attribute__((ext_vector_type(16)));
typedef unsigned int u32x4 __attribute__((ext_vector_type(4)));
typedef unsigned short u16x8 __attribute__((ext_vector_type(8)));

static __device__ __forceinline__ f32x4 zero4() {
    f32x4 z = {0.f, 0.f, 0.f, 0.f}; return z;
}
static __device__ __forceinline__ f32x16 zero16() {
    f32x16 z = {0.f,0.f,0.f,0.f,0.f,0.f,0.f,0.f,
                0.f,0.f,0.f,0.f,0.f,0.f,0.f,0.f};
    return z;
}

// q pre-scale: log2(e) / sqrt(32)
#define QSCALE 0.25505392421795654f

// v_cvt_pk_bf16_f32: dst.lo = bf16(lo), dst.hi = bf16(hi)  (no builtin on gfx950)
#define CVT_PK(dst, lo, hi_) \
    asm("v_cvt_pk_bf16_f32 %0, %1, %2" : "=v"(dst) : "v"(lo), "v"(hi_))
// v_permlane32_swap_b32: x[32:63] <-> y[0:31]
#define PLSWAP(x, y) \
    asm("v_permlane32_swap_b32 %0, %1" : "+v"(x), "+v"(y))

// ---------------------------------------------------------------------------
// ROUND 31: "rest" (qkv+comb+proj) stuck at 85-89us across 4 rounds, ~2.5x
// HBM floors -- they are one-shot kernels with the whole 32KB stage latency-
// exposed before a single barrier. Fix: intra-kernel 2-phase pipelining.
//  qkv: fused-transpose staging split into c-halves; half-1 f32 loads ISSUED
//       before the first barrier (T14 issue-early, held in regs), written to
//       LDS after the kc0..3 compute, second barrier, kc4..7.
//  proj: global_load_lds staging split into kc-halves; half-1 stages issue
//       right after barrier 1, land under kc0..3 MFMAs, vmcnt(0)+barrier.
//  attn: STAGE address math -> running pointers (cuts ~12 VALU/tile).
// attn loop/comb/convw otherwise unchanged (proven R30).
// ---------------------------------------------------------------------------

// ---------------------------------------------------------------------------
// Kernel 0: f32 -> bf16 convert, both weight arrays in one launch.
// ---------------------------------------------------------------------------
__global__ __launch_bounds__(256) void convw_k(const float* __restrict__ s1,
                                               __bf16* __restrict__ d1, int n1,
                                               const float* __restrict__ s2,
                                               __bf16* __restrict__ d2, int n2) {
    const int i = blockIdx.x * 256 + threadIdx.x;
    if (i < n1) d1[i] = (__bf16)s1[i];
    else if (i - n1 < n2) d2[i - n1] = (__bf16)s2[i - n1];
}

// ---------------------------------------------------------------------------
// Kernel 2: QKV GEMM (MFMA) with FUSED transpose+convert staging, 2-phase.
// Block = 64 o x 64 tok. Phase A: stage c[0,128) (f32x4 token-coalesced ->
// cvt -> T), issue c[128,256) loads into regs, barrier, MFMA kc0..3 while
// half-1 loads land; write half 1, barrier, MFMA kc4..7.
// q pre-scaled by QSCALE. qt/kt token-major [bh][n][32], vv d-major.
// grid (NT/64, 768/64, NB), block 256. LDS 33.8 KB.
// ---------------------------------------------------------------------------
__global__ __launch_bounds__(256) void qkv_k(const __bf16* __restrict__ wqkv,
                                             const float* __restrict__ x,
                                             __bf16* __restrict__ qt,
                                             __bf16* __restrict__ kt,
                                             __bf16* __restrict__ vv) {
    __shared__ __align__(16) __bf16 T[64][264];   // [tok][c+pad] 33792 B

    const int tid  = threadIdx.x;
    const int lane = tid & 63, wv = tid >> 6;
    const int g = lane >> 4, c16 = lane & 15;
    const int b    = blockIdx.z;
    const int o0   = blockIdx.y * 64 + wv * 16;
    const int tok0 = blockIdx.x * 64;

    const int tok4 = (tid & 15) * 4;
    const int crow = tid >> 4;                 // 0..15

    // Phase A stage: half 0 (c in [0,128)) load+cvt+write.
    {
#pragma unroll
        for (int i = 0; i < 8; ++i) {
            const int c = i * 16 + crow;
            f32x4 v = *(const f32x4_ma*)&x[((size_t)(b * CC + c)) * NT + tok0 + tok4];
#pragma unroll
            for (int j = 0; j < 4; ++j) T[tok4 + j][c] = (__bf16)v[j];
        }
    }

    // Issue half-1 loads early (held in regs; consumed after first compute).
    f32x4 v1[8];
#pragma unroll
    for (int i = 0; i < 8; ++i) {
        const int c = 128 + i * 16 + crow;
        v1[i] = *(const f32x4_ma*)&x[((size_t)(b * CC + c)) * NT + tok0 + tok4];
    }

    // Preload A rows (o0+c16, all 8 k-chunks).
    const __bf16* arow = wqkv + (size_t)(o0 + c16) * CC + g * 8;
    bf16x8 a[8];
#pragma unroll
    for (int kc = 0; kc < 8; ++kc) a[kc] = *(const bf16x8_ma*)(arow + kc * 32);

    __syncthreads();   // half 0 visible (drains all outstanding loads too)

    f32x4 acc[4];
#pragma unroll
    for (int i = 0; i < 4; ++i) acc[i] = zero4();

#pragma unroll
    for (int kc = 0; kc < 4; ++kc) {
#pragma unroll
        for (int js = 0; js < 4; ++js) {
            bf16x8 bb = *(const bf16x8_ma*)&T[js * 16 + c16][kc * 32 + g * 8];
            acc[js] = __builtin_amdgcn_mfma_f32_16x16x32_bf16(a[kc], bb, acc[js], 0, 0, 0);
        }
    }

    // Write half 1 (v1 already in regs/in flight).
#pragma unroll
    for (int i = 0; i < 8; ++i) {
        const int c = 128 + i * 16 + crow;
#pragma unroll
        for (int j = 0; j < 4; ++j) T[tok4 + j][c] = (__bf16)v1[i][j];
    }
    __syncthreads();   // half 1 visible

#pragma unroll
    for (int kc = 4; kc < 8; ++kc) {
#pragma unroll
        for (int js = 0; js < 4; ++js) {
            bf16x8 bb = *(const bf16x8_ma*)&T[js * 16 + c16][kc * 32 + g * 8];
            acc[js] = __builtin_amdgcn_mfma_f32_16x16x32_bf16(a[kc], bb, acc[js], 0, 0, 0);
        }
    }

    const int reg = o0 >> 8;                 // 0=q, 1=k, 2=v (wave-uniform)
    const int oo0 = (o0 & 255) + g * 4;
    const int h   = oo0 >> 5;
    const int dd0 = oo0 & 31;
    const size_t bh = (size_t)(b * NHD + h);

#pragma unroll
    for (int js = 0; js < 4; ++js) {
        const int tok = tok0 + js * 16 + c16;
        if (reg == 0) {
            bf16x4 pk;
#pragma unroll
            for (int r = 0; r < 4; ++r) pk[r] = (__bf16)(acc[js][r] * QSCALE);
            *(bf16x4_ma*)(qt + (bh * NT + tok) * HD + dd0) = pk;
        } else if (reg == 1) {
            bf16x4 pk;
#pragma unroll
            for (int r = 0; r < 4; ++r) pk[r] = (__bf16)acc[js][r];
            *(bf16x4_ma*)(kt + (bh * NT + tok) * HD + dd0) = pk;
        } else {
#pragma unroll
            for (int r = 0; r < 4; ++r)
                vv[(bh * HD + dd0 + r) * NT + tok] = (__bf16)acc[js][r];
        }
    }
}

// ---------------------------------------------------------------------------
// Kernel 3: MFMA flash attention, 32x32 swapped-operand, in-register P,
// block-shared LDS K/V (2-phase), 128-j tiles, l on the MFMA pipe (ones-B).
// STAGE uses running pointers (kp += 128*HD, vp += 128) -- no per-tile muls.
// Block 256 = 4 waves x 32 q = 128 q/block; block sweeps its j-segment.
// nseg>1: f32 partial (O,l) to PO/PL; nseg=1: ao directly.
// grid (NT/128, NB*NHD, JSEG), LDS 32KB.
// ---------------------------------------------------------------------------
__global__ __launch_bounds__(256, 4) void attn_k(const __bf16* __restrict__ qt,
                                                 const __bf16* __restrict__ kt,
                                                 const __bf16* __restrict__ vv,
                                                 __bf16* __restrict__ ao,
                                                 float* __restrict__ PO,
                                                 float* __restrict__ PL) {
    // Fragment lane-order tiles: [buf][js][half][lane*8 bf16]
    __shared__ __align__(16) __bf16 KF[2][4][2][512];   // 16 KB
    __shared__ __align__(16) __bf16 VF[2][4][2][512];   // 16 KB

    const int tid  = threadIdx.x;
    const int lane = tid & 63, wv = tid >> 6;          // wv 0..3
    const int c32 = lane & 31, hi = lane >> 5;
    const int bh = blockIdx.y;
    const int b = bh >> 3, h = bh & 7;
    const int seg = blockIdx.z, nseg = gridDim.z;
    const int i0q = blockIdx.x * 128 + wv * 32;        // this wave: 32 queries

    const __bf16* qbase = qt + ((size_t)bh * NT + i0q) * HD;
    const __bf16* kbase = kt + (size_t)bh * NT * HD;
    const __bf16* vbase = vv + (size_t)bh * HD * NT;

    // Q fragments (B operand of score MFMA): row=q=c32, k = kk*16 + hi*8 + e
    bf16x8 aq0 = *(const bf16x8_ma*)(qbase + (size_t)c32 * HD + hi * 8);
    bf16x8 aq1 = *(const bf16x8_ma*)(qbase + (size_t)c32 * HD + 16 + hi * 8);

    // All-ones bf16 B operand (layout-independent: every element is 1.0).
    u16x8 ones_u = {0x3F80,0x3F80,0x3F80,0x3F80,0x3F80,0x3F80,0x3F80,0x3F80};
    const bf16x8 ones = __builtin_bit_cast(bf16x8, ones_u);

    f32x16 oacc = zero16();      // D[q_row][d_col]: rows=q, cols=d=c32
    f32x16 lacc = zero16();      // row-sums of P, replicated across cols

    const int ntiles  = (NT / 128) / nseg;         // 16 @ jseg=2, 32 @ jseg=1
    const int j_begin = seg * ntiles * 128;

    // Running stage pointers for the NEXT tile to stage.
    const __bf16* kp = kbase + (size_t)(j_begin + wv * 32 + c32) * HD + hi * 8;
    const __bf16* vp = vbase + (size_t)c32 * NT + j_begin + wv * 32 + hi * 8;

#define STAGE(bf) do {                                                                  \
    __builtin_amdgcn_global_load_lds(                                                   \
        (const __attribute__((address_space(1))) void*)kp,                              \
        (__attribute__((address_space(3))) void*)&KF[bf][wv][0][0],                     \
        16, 0, 0);                                                                      \
    __builtin_amdgcn_global_load_lds(                                                   \
        (const __attribute__((address_space(1))) void*)(kp + 16),                       \
        (__attribute__((address_space(3))) void*)&KF[bf][wv][1][0],                     \
        16, 0, 0);                                                                      \
    __builtin_amdgcn_global_load_lds(                                                   \
        (const __attribute__((address_space(1))) void*)vp,                              \
        (__attribute__((address_space(3))) void*)&VF[bf][wv][0][0],                     \
        16, 0, 0);                                                                      \
    __builtin_amdgcn_global_load_lds(                                                   \
        (const __attribute__((address_space(1))) void*)(vp + 16),                       \
        (__attribute__((address_space(3))) void*)&VF[bf][wv][1][0],                     \
        16, 0, 0);                                                                      \
    kp += (size_t)128 * HD;                                                             \
    vp += 128;                                                                          \
} while (0)

#define SUBTILE(bf, js) do {                                                            \
    bf16x8 fk0 = *(const bf16x8_ma*)&KF[bf][js][0][lane * 8];                           \
    bf16x8 fk1 = *(const bf16x8_ma*)&KF[bf][js][1][lane * 8];                           \
    bf16x8 fv0 = *(const bf16x8_ma*)&VF[bf][js][0][lane * 8];                           \
    bf16x8 fv1 = *(const bf16x8_ma*)&VF[bf][js][1][lane * 8];                           \
    f32x16 s = __builtin_amdgcn_mfma_f32_32x32x16_bf16(fk0, aq0, zero16(), 0, 0, 0);    \
    s = __builtin_amdgcn_mfma_f32_32x32x16_bf16(fk1, aq1, s, 0, 0, 0);                  \
    float p[16];                                                                        \
    _Pragma("unroll")                                                                   \
    for (int r = 0; r < 16; ++r) p[r] = __builtin_amdgcn_exp2f(s[r]);                   \
    unsigned pk[8];                                                                     \
    _Pragma("unroll")                                                                   \
    for (int i = 0; i < 8; ++i) CVT_PK(pk[i], p[2 * i], p[2 * i + 1]);                  \
    PLSWAP(pk[0], pk[2]);                                                               \
    PLSWAP(pk[1], pk[3]);                                                               \
    PLSWAP(pk[4], pk[6]);                                                               \
    PLSWAP(pk[5], pk[7]);                                                               \
    u32x4 a0 = {pk[0], pk[1], pk[2], pk[3]};                                            \
    u32x4 a1 = {pk[4], pk[5], pk[6], pk[7]};                                            \
    const bf16x8 ap0 = __builtin_bit_cast(bf16x8, a0);                                  \
    const bf16x8 ap1 = __builtin_bit_cast(bf16x8, a1);                                  \
    oacc = __builtin_amdgcn_mfma_f32_32x32x16_bf16(ap0, fv0, oacc, 0, 0, 0);            \
    oacc = __builtin_amdgcn_mfma_f32_32x32x16_bf16(ap1, fv1, oacc, 0, 0, 0);            \
    lacc = __builtin_amdgcn_mfma_f32_32x32x16_bf16(ap0, ones, lacc, 0, 0, 0);           \
    lacc = __builtin_amdgcn_mfma_f32_32x32x16_bf16(ap1, ones, lacc, 0, 0, 0);           \
} while (0)

    // Prologue: stage tile 0 into buf 0.
    STAGE(0);
    asm volatile("s_waitcnt vmcnt(0)" ::: "memory");
    __syncthreads();

    int buf = 0;
#pragma unroll 1
    for (int t = 0; t < ntiles; ++t) {
        if (t + 1 < ntiles) STAGE(buf ^ 1);
        SUBTILE(buf, 0);
        SUBTILE(buf, 1);
        SUBTILE(buf, 2);
        SUBTILE(buf, 3);
        asm volatile("s_waitcnt vmcnt(0)" ::: "memory");
        __syncthreads();
        buf ^= 1;
    }

#undef STAGE
#undef SUBTILE

    if (nseg == 1) {
        // Direct epilogue: oacc/lacc rows q = 8*g4 + 4*hi + r, cols d = c32.
#pragma unroll
        for (int g4 = 0; g4 < 4; ++g4) {
#pragma unroll
            for (int r = 0; r < 4; ++r) {
                const int q = 8 * g4 + 4 * hi + r;
                ao[((size_t)(b * NT) + i0q + q) * CC + h * HD + c32] =
                    (__bf16)(oacc[4 * g4 + r] / lacc[4 * g4 + r]);
            }
        }
    } else {
        // Partial epilogue: PO [seg][bh][n][32] f32, PL [seg][bh][n] f32.
        float* po = PO + (((size_t)seg * NB * NHD + bh) * NT + i0q) * HD;
#pragma unroll
        for (int g4 = 0; g4 < 4; ++g4) {
#pragma unroll
            for (int r = 0; r < 4; ++r) {
                const int q = 8 * g4 + 4 * hi + r;
                po[(size_t)q * HD + c32] = oacc[4 * g4 + r];
            }
        }
        if (c32 == 0) {
            float* pl = PL + ((size_t)seg * NB * NHD + bh) * NT + i0q;
#pragma unroll
            for (int g4 = 0; g4 < 4; ++g4)
#pragma unroll
                for (int r = 0; r < 4; ++r)
                    pl[8 * g4 + 4 * hi + r] = lacc[4 * g4 + r];
        }
    }
}

// ---------------------------------------------------------------------------
// Kernel 3b: combine nseg partials: ao = (Sum O_s)/(Sum l_s), bf16.
// One thread = 4 consecutive d of one (bh, n). grid 2048 x 256.
// ---------------------------------------------------------------------------
__global__ __launch_bounds__(256) void comb_k(const float* __restrict__ PO,
                                              const float* __restrict__ PL,
                                              __bf16* __restrict__ ao,
                                              int nseg) {
    const int i = blockIdx.x * 256 + threadIdx.x;    // 0 .. 16*4096*8-1
    const int bh = i >> 15;                          // 8 groups * 4096 n
    const int rem = i & 32767;
    const int n = rem >> 3, g = rem & 7;
    const int b = bh >> 3, h = bh & 7;

    const size_t SEGO = (size_t)(NB * NHD) * NT * HD;
    const size_t SEGL = (size_t)(NB * NHD) * NT;
    const size_t o0i = (((size_t)bh) * NT + n) * HD + g * 4;
    const size_t li  = (size_t)bh * NT + n;

    f32x4 o = *(const f32x4_ma*)&PO[o0i];
    float l = PL[li];
#pragma unroll 3
    for (int s = 1; s < nseg; ++s) {
        o += *(const f32x4_ma*)&PO[(size_t)s * SEGO + o0i];
        l += PL[(size_t)s * SEGL + li];
    }

    bf16x4 pk;
#pragma unroll
    for (int r = 0; r < 4; ++r) pk[r] = (__bf16)(o[r] / l);
    *(bf16x4_ma*)&ao[((size_t)(b * NT) + n) * CC + h * HD + g * 4] = pk;
}

// ---------------------------------------------------------------------------
// Kernel 4: proj GEMM + residual (MFMA), F32 output, B-tile LDS-shared,
// 2-phase staging (half 1 lands under kc0..3 compute).
// grid (NT/64, CC/64, NB), block 256.
// ---------------------------------------------------------------------------
__global__ __launch_bounds__(256) void proj_k(const __bf16* __restrict__ wp,
                                              const __bf16* __restrict__ ao,
                                              const float* __restrict__ x,
                                              float* __restrict__ out) {
    __shared__ __align__(16) __bf16 BF[4][8][512];   // [js][kc][lane*8] 32 KB

    const int lane = threadIdx.x & 63, wv = threadIdx.x >> 6;
    const int g = lane >> 4, c16 = lane & 15;
    const int b    = blockIdx.z;
    const int o0   = blockIdx.y * 64 + wv * 16;
    const int tok0 = blockIdx.x * 64;

    const __bf16* bsrc = ao + ((size_t)(b * NT + tok0 + wv * 16 + c16)) * CC + g * 8;
    // Stage half 0 (kc 0..3).
#pragma unroll
    for (int kc = 0; kc < 4; ++kc) {
        __builtin_amdgcn_global_load_lds(
            (const __attribute__((address_space(1))) void*)(bsrc + kc * 32),
            (__attribute__((address_space(3))) void*)&BF[wv][kc][0],
            16, 0, 0);
    }

    const __bf16* arow = wp + (size_t)(o0 + c16) * CC + g * 8;
    bf16x8 a[8];
#pragma unroll
    for (int kc = 0; kc < 8; ++kc) a[kc] = *(const bf16x8_ma*)(arow + kc * 32);

    __syncthreads();   // half 0 + A ready (vmcnt(0) drain)

    // Stage half 1 (kc 4..7) -- lands under the kc0..3 MFMAs.
#pragma unroll
    for (int kc = 4; kc < 8; ++kc) {
        __builtin_amdgcn_global_load_lds(
            (const __attribute__((address_space(1))) void*)(bsrc + kc * 32),
            (__attribute__((address_space(3))) void*)&BF[wv][kc][0],
            16, 0, 0);
    }

    f32x4 acc[4];
#pragma unroll
    for (int i = 0; i < 4; ++i) acc[i] = zero4();

#pragma unroll
    for (int kc = 0; kc < 4; ++kc) {
#pragma unroll
        for (int js = 0; js < 4; ++js) {
            bf16x8 bb = *(const bf16x8_ma*)&BF[js][kc][lane * 8];
            acc[js] = __builtin_amdgcn_mfma_f32_16x16x32_bf16(a[kc], bb, acc[js], 0, 0, 0);
        }
    }

    asm volatile("s_waitcnt vmcnt(0)" ::: "memory");
    __syncthreads();   // half 1 ready

#pragma unroll
    for (int kc = 4; kc < 8; ++kc) {
#pragma unroll
        for (int js = 0; js < 4; ++js) {
            bf16x8 bb = *(const bf16x8_ma*)&BF[js][kc][lane * 8];
            acc[js] = __builtin_amdgcn_mfma_f32_16x16x32_bf16(a[kc], bb, acc[js], 0, 0, 0);
        }
    }

#pragma unroll
    for (int js = 0; js < 4; ++js) {
        const int tok = tok0 + js * 16 + c16;
#pragma unroll
        for (int r = 0; r < 4; ++r) {
            const int o = o0 + g * 4 + r;
            const size_t idx = ((size_t)(b * CC + o)) * NT + tok;
            out[idx] = acc[js][r] + x[idx];
        }
    }
}

// ---------------------------------------------------------------------------
extern "C" void kernel_launch(void* const* d_in, const int* in_sizes, int n_in,
                              void* d_out, int out_size, void* d_ws, size_t ws_size,
                              hipStream_t stream) {
    const int SX  = NB * CC * NT;   // 2,097,152
    const int SW3 = 3 * CC * CC;    //   196,608
    const int SW1 = CC * CC;        //    65,536
    const size_t E = (size_t)SX;

    const float* x  = nullptr;
    const float* wq = nullptr;
    const float* wp = nullptr;
    for (int i = 0; i < n_in; ++i) {
        const int sz = in_sizes[i];
        if (sz == SX || sz == 2 * SX || sz == 4 * SX)           x  = (const float*)d_in[i];
        else if (sz == SW3 || sz == 2 * SW3 || sz == 4 * SW3)   wq = (const float*)d_in[i];
        else if (sz == SW1 || sz == 2 * SW1 || sz == 4 * SW1)   wp = (const float*)d_in[i];
    }
    if (!x || !wq || !wp) {
        x  = (const float*)d_in[0];
        wq = (const float*)d_in[1];
        wp = (const float*)d_in[2];
    }

    // Workspace (bf16 elements):
    __bf16* ws  = (__bf16*)d_ws;
    __bf16* wqb = ws;
    __bf16* wpb = wqb + SW3;
    __bf16* ao  = wpb + SW1;
    __bf16* qt  = ao + E;
    __bf16* kt  = qt + E;
    __bf16* vv  = kt + E;

    // Optional JSEG partial buffers (f32), appended after vv:
    const size_t baseB = (size_t)(SW3 + SW1) * 2 + 4 * E * 2;       // bytes used
    const size_t segoB = (size_t)NB * NHD * NT * HD * 4;            // 8.39 MB/seg
    const size_t seglB = (size_t)NB * NHD * NT * 4;                 // 0.26 MB/seg
    const int jseg = (ws_size >= baseB + 2 * (segoB + seglB)) ? 2 : 1;
    float* PO = (float*)((char*)d_ws + baseB);
    float* PL = (float*)((char*)d_ws + baseB + (size_t)jseg * segoB);

    float* out = (float*)d_out;

    convw_k<<<dim3((SW3 + SW1 + 255) / 256), 256, 0, stream>>>(wq, wqb, SW3, wp, wpb, SW1);
    qkv_k<<<dim3(NT / 64, (3 * CC) / 64, NB), 256, 0, stream>>>(wqb, x, qt, kt, vv);
    attn_k<<<dim3(NT / 128, NB * NHD, jseg), 256, 0, stream>>>(qt, kt, vv, ao, PO, PL);
    if (jseg > 1)
        comb_k<<<dim3((NB * NHD * NT * (HD / 4)) / 256), 256, 0, stream>>>(PO, PL, ao, jseg);
    proj_k<<<dim3(NT / 64, CC / 64, NB), 256, 0, stream>>>(wpb, ao, x, out);
}